// Round 3
// baseline (1452.799 us; speedup 1.0000x reference)
//
#include <hip/hip_runtime.h>
#include <hip/hip_bf16.h>

#define BSZ 2
#define LLEN 2048
#define NHEADS 32
#define HEADDIM 64
#define DSTATE 128
#define DCONV 4
#define DINNER (NHEADS * HEADDIM)                  // 2048
#define DPROJ  (2 * DINNER + 2 * DSTATE + NHEADS)  // 4384

__device__ __forceinline__ float bf2f(__hip_bfloat16 x) { return __bfloat162float(x); }
__device__ __forceinline__ float sigm(float x) { return 1.0f / (1.0f + __expf(-x)); }

// dtype-adaptive element load: F32 -> float array, else bf16 array.
template<bool F32>
__device__ __forceinline__ float ld(const void* p, size_t i) {
    return F32 ? ((const float*)p)[i] : bf2f(((const __hip_bfloat16*)p)[i]);
}

// Robust python-int scalar read (int32 bits or float32 bits).
__device__ __forceinline__ float int_scalar(const int* p) {
    int i = *p;
    if (i >= 0 && i <= 1000000) return (float)i;
    return __int_as_float(i);
}

// ---------------------------------------------------------------------------
// Kernel 0: dtype detector. Interpret first 16384 elements of zxbcdt as bf16;
// N(0,1) bf16 data never has exponent 0xFF, while fp32 data misread as bf16
// hits 0xFF (NaN/Inf pattern) w.p. ~1/256 per element. flag=1 -> fp32 world.
// ---------------------------------------------------------------------------
__global__ __launch_bounds__(256) void detect_kernel(
    const unsigned short* __restrict__ zx_u16, int* __restrict__ flag)
{
    __shared__ int s;
    if (threadIdx.x == 0) s = 0;
    __syncthreads();
    int bad = 0;
    for (int i = threadIdx.x; i < 16384; i += 256) {
        if (((zx_u16[i] >> 7) & 0xFF) == 0xFF) bad = 1;
    }
    if (bad) atomicOr(&s, 1);
    __syncthreads();
    if (threadIdx.x == 0) *flag = s;
}

// ---------------------------------------------------------------------------
// Kernel 1: B/C conv channels + dt/dA into fp32 workspace (5 MiB).
// ---------------------------------------------------------------------------
template<bool F32>
__device__ __forceinline__ void pre_body(
    const void* __restrict__ zx, const void* __restrict__ cw,
    const void* __restrict__ cb, const void* __restrict__ dtb,
    const void* __restrict__ alog, const void* __restrict__ dts,
    const int* __restrict__ mn_p, const int* __restrict__ mx_p,
    float* __restrict__ Bc, float* __restrict__ Cc,
    float* __restrict__ dtc, float* __restrict__ dAc)
{
    const int bl  = blockIdx.x;            // 0 .. B*L-1
    const int b   = bl / LLEN;
    const int l   = bl % LLEN;
    const int tid = threadIdx.x;           // 0..255 == 2*DSTATE channels

    {
        const int c = DINNER + tid;        // conv channel (B/C region)
        float acc = ld<F32>(cb, c);
        #pragma unroll
        for (int k = 0; k < DCONV; k++) {
            int lk = l - (DCONV - 1) + k;
            if (lk >= 0) {
                acc += ld<F32>(cw, (size_t)c * DCONV + k) *
                       ld<F32>(zx, ((size_t)b * LLEN + lk) * DPROJ + DINNER + c);
            }
        }
        float v = acc * sigm(acc);
        if (tid < DSTATE) Bc[(size_t)bl * DSTATE + tid] = v;
        else              Cc[(size_t)bl * DSTATE + (tid - DSTATE)] = v;
    }

    if (tid < NHEADS) {
        float raw = ld<F32>(zx, (size_t)bl * DPROJ + (DPROJ - NHEADS) + tid);
        float v   = raw * ld<F32>(dts, tid) + ld<F32>(dtb, tid);
        float sp  = (v > 20.0f) ? v : log1pf(__expf(v));
        float dt  = fminf(fmaxf(sp, int_scalar(mn_p)), int_scalar(mx_p));
        float A   = -__expf(ld<F32>(alog, tid));
        dtc[(size_t)bl * NHEADS + tid] = dt;
        dAc[(size_t)bl * NHEADS + tid] = __expf(dt * A);
    }
}

__global__ __launch_bounds__(256) void pre_kernel(
    const void* zx, const void* cw, const void* cb, const void* dtb,
    const void* alog, const void* dts, const int* mn_p, const int* mx_p,
    const int* __restrict__ flag,
    float* Bc, float* Cc, float* dtc, float* dAc)
{
    if (*flag) pre_body<true >(zx, cw, cb, dtb, alog, dts, mn_p, mx_p, Bc, Cc, dtc, dAc);
    else       pre_body<false>(zx, cw, cb, dtb, alog, dts, mn_p, mx_p, Bc, Cc, dtc, dAc);
}

// ---------------------------------------------------------------------------
// Kernel 2: sequential selective scan; x-conv + silu(z) fused in-register.
// Grid (4,32,2)=256 WGs x 256 thr (1 WG/CU). Wave owns 4 p's; lane=(ng<<2)|p.
// ---------------------------------------------------------------------------
template<bool F32>
__device__ __forceinline__ void scan_body(
    const void* __restrict__ zx, const void* __restrict__ cw,
    const void* __restrict__ cb,
    const float* __restrict__ Bc, const float* __restrict__ Cc,
    const float* __restrict__ dtc, const float* __restrict__ dAc,
    const void* __restrict__ d_param, const void* __restrict__ init_state,
    void* __restrict__ outp)
{
    const int pb   = blockIdx.x;        // 0..3
    const int h    = blockIdx.y;        // 0..31
    const int b    = blockIdx.z;        // 0..1
    const int tid  = threadIdx.x;
    const int wave = tid >> 6;
    const int lane = tid & 63;
    const int p    = pb * 16 + wave * 4 + (lane & 3);   // 0..63
    const int ng   = lane >> 2;                         // 0..15
    const int n0   = ng * 8;

    const int cx = h * HEADDIM + p;                     // x/z channel
    const float w0 = ld<F32>(cw, (size_t)cx * DCONV + 0);
    const float w1 = ld<F32>(cw, (size_t)cx * DCONV + 1);
    const float w2 = ld<F32>(cw, (size_t)cx * DCONV + 2);
    const float w3 = ld<F32>(cw, (size_t)cx * DCONV + 3);
    const float bx = ld<F32>(cb, cx);

    float st[8];
    {
        size_t sbase = (((size_t)b * NHEADS + h) * HEADDIM + p) * DSTATE + n0;
        #pragma unroll
        for (int j = 0; j < 8; j++) st[j] = ld<F32>(init_state, sbase + j);
    }
    const float Dh = ld<F32>(d_param, h);

    const size_t row0    = (size_t)b * LLEN * DPROJ;
    const int    col_z   = cx;
    const int    col_x   = DINNER + cx;
    const size_t bc_base = (size_t)b * LLEN * DSTATE + n0;
    const size_t dt_base = (size_t)b * LLEN * NHEADS + h;

    float xh0 = 0.0f, xh1 = 0.0f, xh2 = 0.0f;   // conv history (zero pad)
    float xraw = ld<F32>(zx, row0 + col_x);
    float zraw = ld<F32>(zx, row0 + col_z);
    float4 b0 = *(const float4*)(Bc + bc_base);
    float4 b1 = *(const float4*)(Bc + bc_base + 4);
    float4 c0 = *(const float4*)(Cc + bc_base);
    float4 c1 = *(const float4*)(Cc + bc_base + 4);
    float dtv = dtc[dt_base];
    float dAv = dAc[dt_base];

    for (int t = 0; t < LLEN; t++) {
        // prefetch t+1 (clamped re-read on last iter; harmless)
        const int tn = (t + 1 < LLEN) ? (t + 1) : t;
        const size_t rown = row0 + (size_t)tn * DPROJ;
        const size_t bcn  = bc_base + (size_t)tn * DSTATE;
        float  nxraw = ld<F32>(zx, rown + col_x);
        float  nzraw = ld<F32>(zx, rown + col_z);
        float4 nb0 = *(const float4*)(Bc + bcn);
        float4 nb1 = *(const float4*)(Bc + bcn + 4);
        float4 nc0 = *(const float4*)(Cc + bcn);
        float4 nc1 = *(const float4*)(Cc + bcn + 4);
        float  ndt = dtc[dt_base + (size_t)tn * NHEADS];
        float  ndA = dAc[dt_base + (size_t)tn * NHEADS];

        // fused depthwise conv4 + silu -> x
        float cv = bx + w0 * xh0 + w1 * xh1 + w2 * xh2 + w3 * xraw;
        float xv = cv * sigm(cv);
        const float coef = dtv * xv;

        const float Bv[8] = {b0.x, b0.y, b0.z, b0.w, b1.x, b1.y, b1.z, b1.w};
        const float Cv[8] = {c0.x, c0.y, c0.z, c0.w, c1.x, c1.y, c1.z, c1.w};
        float acc0 = 0.0f, acc1 = 0.0f;
        #pragma unroll
        for (int j = 0; j < 4; j++) {
            st[j] = dAv * st[j] + coef * Bv[j];
            acc0 += st[j] * Cv[j];
        }
        #pragma unroll
        for (int j = 4; j < 8; j++) {
            st[j] = dAv * st[j] + coef * Bv[j];
            acc1 += st[j] * Cv[j];
        }
        float acc = acc0 + acc1;
        acc += __shfl_xor(acc, 4, 64);
        acc += __shfl_xor(acc, 8, 64);
        acc += __shfl_xor(acc, 16, 64);
        acc += __shfl_xor(acc, 32, 64);

        if (ng == 0) {
            size_t oi = ((size_t)b * LLEN + t) * DINNER + cx;
            float y  = acc + Dh * xv;
            float zg = zraw * sigm(zraw);
            float r  = y * zg;
            if (F32) ((float*)outp)[oi] = r;
            else     ((__hip_bfloat16*)outp)[oi] = __float2bfloat16(r);
        }

        xh0 = xh1; xh1 = xh2; xh2 = xraw;
        xraw = nxraw; zraw = nzraw;
        b0 = nb0; b1 = nb1; c0 = nc0; c1 = nc1;
        dtv = ndt; dAv = ndA;
    }
}

__global__ __launch_bounds__(256) void scan_kernel(
    const void* zx, const void* cw, const void* cb,
    const float* Bc, const float* Cc, const float* dtc, const float* dAc,
    const void* d_param, const void* init_state, const int* __restrict__ flag,
    void* outp)
{
    if (*flag) scan_body<true >(zx, cw, cb, Bc, Cc, dtc, dAc, d_param, init_state, outp);
    else       scan_body<false>(zx, cw, cb, Bc, Cc, dtc, dAc, d_param, init_state, outp);
}

// ---------------------------------------------------------------------------
extern "C" void kernel_launch(void* const* d_in, const int* in_sizes, int n_in,
                              void* d_out, int out_size, void* d_ws, size_t ws_size,
                              hipStream_t stream) {
    const void* zxbcdt   = d_in[0];
    const void* conv_w   = d_in[1];
    const void* conv_b   = d_in[2];
    const void* dt_bias  = d_in[3];
    const void* a_log    = d_in[4];
    const void* d_param  = d_in[5];
    const void* dt_scale = d_in[6];
    const void* init_st  = d_in[7];
    const int* dt_min_p  = (const int*)d_in[11];
    const int* dt_max_p  = (const int*)d_in[12];

    // workspace: 5 MiB + flag
    char* ws = (char*)d_ws;
    const size_t n_bl = (size_t)BSZ * LLEN;               // 4096
    float* Bc = (float*)ws;  ws += n_bl * DSTATE * sizeof(float);   // 2 MiB
    float* Cc = (float*)ws;  ws += n_bl * DSTATE * sizeof(float);   // 2 MiB
    float* dtc = (float*)ws; ws += n_bl * NHEADS * sizeof(float);   // 0.5 MiB
    float* dAc = (float*)ws; ws += n_bl * NHEADS * sizeof(float);   // 0.5 MiB
    int* flag = (int*)ws;

    detect_kernel<<<1, 256, 0, stream>>>((const unsigned short*)zxbcdt, flag);

    pre_kernel<<<dim3((unsigned)n_bl), 256, 0, stream>>>(
        zxbcdt, conv_w, conv_b, dt_bias, a_log, dt_scale,
        dt_min_p, dt_max_p, flag, Bc, Cc, dtc, dAc);

    scan_kernel<<<dim3(4, NHEADS, BSZ), 256, 0, stream>>>(
        zxbcdt, conv_w, conv_b, Bc, Cc, dtc, dAc,
        d_param, init_st, flag, d_out);
}

// Round 4
// 1135.571 us; speedup vs baseline: 1.2794x; 1.2794x over previous
//
#include <hip/hip_runtime.h>
#include <hip/hip_bf16.h>

#define BSZ 2
#define LLEN 2048
#define NHEADS 32
#define HEADDIM 64
#define DSTATE 128
#define DCONV 4
#define DINNER (NHEADS * HEADDIM)                  // 2048
#define DPROJ  (2 * DINNER + 2 * DSTATE + NHEADS)  // 4384
#define DEPTH 8                                    // prefetch ring depth

__device__ __forceinline__ float sigm(float x) { return 1.0f / (1.0f + __expf(-x)); }

// Robust python-int scalar read (int32 bits or float32 bits).
__device__ __forceinline__ float int_scalar(const int* p) {
    int i = *p;
    if (i >= 0 && i <= 1000000) return (float)i;
    return __int_as_float(i);
}

// ---------------------------------------------------------------------------
// Kernel 1: B/C conv channels + dt/dA into fp32 workspace (5 MiB).
//   grid = B*L blocks x 256 threads. tid -> conv channel DINNER+tid
//   (bias + causal conv4 + silu) -> Bc / Cc. tid < 32 -> dtA = (dt, exp(dt*A)).
// ---------------------------------------------------------------------------
__global__ __launch_bounds__(256) void pre_kernel(
    const float* __restrict__ zx, const float* __restrict__ cw,
    const float* __restrict__ cb, const float* __restrict__ dtb,
    const float* __restrict__ alog, const float* __restrict__ dts,
    const int* __restrict__ mn_p, const int* __restrict__ mx_p,
    float* __restrict__ Bc, float* __restrict__ Cc,
    float2* __restrict__ dtA)
{
    const int bl  = blockIdx.x;            // 0 .. B*L-1
    const int b   = bl / LLEN;
    const int l   = bl % LLEN;
    const int tid = threadIdx.x;           // 0..255 == 2*DSTATE channels

    {
        const int c = DINNER + tid;        // conv channel (B/C region)
        float acc = cb[c];
        #pragma unroll
        for (int k = 0; k < DCONV; k++) {
            int lk = l - (DCONV - 1) + k;
            if (lk >= 0) {
                acc += cw[(size_t)c * DCONV + k] *
                       zx[((size_t)b * LLEN + lk) * DPROJ + DINNER + c];
            }
        }
        float v = acc * sigm(acc);
        if (tid < DSTATE) Bc[(size_t)bl * DSTATE + tid] = v;
        else              Cc[(size_t)bl * DSTATE + (tid - DSTATE)] = v;
    }

    if (tid < NHEADS) {
        float raw = zx[(size_t)bl * DPROJ + (DPROJ - NHEADS) + tid];
        float v   = raw * dts[tid] + dtb[tid];
        float sp  = (v > 20.0f) ? v : log1pf(__expf(v));
        float dt  = fminf(fmaxf(sp, int_scalar(mn_p)), int_scalar(mx_p));
        float A   = -__expf(alog[tid]);
        dtA[(size_t)bl * NHEADS + tid] = make_float2(dt, __expf(dt * A));
    }
}

// ---------------------------------------------------------------------------
// Kernel 2: sequential selective scan, depth-8 register-ring prefetch.
// Grid (4,32,2)=256 WGs x 256 thr (1 WG/CU). Wave owns 4 p's; lane=(ng<<2)|p.
// Loop unrolled x8: slot u holds t=tb+u in regs; after consuming, slot u
// issues loads for t+8 -> 56 outstanding VMEM/wave (vmcnt cap is 63).
// ---------------------------------------------------------------------------
__global__ __launch_bounds__(256, 1) void scan_kernel(
    const float* __restrict__ zx, const float* __restrict__ cw,
    const float* __restrict__ cb,
    const float* __restrict__ Bc, const float* __restrict__ Cc,
    const float2* __restrict__ dtA,
    const float* __restrict__ d_param, const float* __restrict__ init_state,
    float* __restrict__ out)
{
    const int pb   = blockIdx.x;        // 0..3
    const int h    = blockIdx.y;        // 0..31
    const int b    = blockIdx.z;        // 0..1
    const int tid  = threadIdx.x;
    const int wave = tid >> 6;
    const int lane = tid & 63;
    const int p    = pb * 16 + wave * 4 + (lane & 3);   // 0..63
    const int ng   = lane >> 2;                         // 0..15
    const int n0   = ng * 8;

    const int cx = h * HEADDIM + p;                     // x/z channel
    const float w0 = cw[(size_t)cx * DCONV + 0];
    const float w1 = cw[(size_t)cx * DCONV + 1];
    const float w2 = cw[(size_t)cx * DCONV + 2];
    const float w3 = cw[(size_t)cx * DCONV + 3];
    const float bx = cb[cx];

    float st[8];
    {
        size_t sbase = (((size_t)b * NHEADS + h) * HEADDIM + p) * DSTATE + n0;
        #pragma unroll
        for (int j = 0; j < 8; j++) st[j] = init_state[sbase + j];
    }
    const float Dh = d_param[h];

    const size_t row0    = (size_t)b * LLEN * DPROJ;
    const int    col_z   = cx;
    const int    col_x   = DINNER + cx;
    const size_t bc_base = (size_t)b * LLEN * DSTATE + n0;
    const size_t dt_base = (size_t)b * LLEN * NHEADS + h;
    const size_t o_base  = (size_t)b * LLEN * DINNER + cx;

    // prefetch ring: slot u holds step tb+u
    float4 rb0[DEPTH], rb1[DEPTH], rc0[DEPTH], rc1[DEPTH];
    float  rx[DEPTH], rz[DEPTH];
    float2 rda[DEPTH];

    #pragma unroll
    for (int u = 0; u < DEPTH; u++) {
        const size_t bcn = bc_base + (size_t)u * DSTATE;
        rb0[u] = *(const float4*)(Bc + bcn);
        rb1[u] = *(const float4*)(Bc + bcn + 4);
        rc0[u] = *(const float4*)(Cc + bcn);
        rc1[u] = *(const float4*)(Cc + bcn + 4);
        rx[u]  = zx[row0 + (size_t)u * DPROJ + col_x];
        rz[u]  = zx[row0 + (size_t)u * DPROJ + col_z];
        rda[u] = dtA[dt_base + (size_t)u * NHEADS];
    }

    float xh0 = 0.0f, xh1 = 0.0f, xh2 = 0.0f;   // conv history (zero pad)

    for (int tb = 0; tb < LLEN; tb += DEPTH) {
        #pragma unroll
        for (int u = 0; u < DEPTH; u++) {
            const int t = tb + u;
            // consume slot u
            const float4 b0 = rb0[u], b1 = rb1[u];
            const float4 c0 = rc0[u], c1 = rc1[u];
            const float  xraw = rx[u], zraw = rz[u];
            const float2 da   = rda[u];

            // issue prefetch for t+DEPTH into slot u (clamped; tail unused)
            {
                int tn = t + DEPTH; if (tn >= LLEN) tn = LLEN - 1;
                const size_t bcn = bc_base + (size_t)tn * DSTATE;
                rb0[u] = *(const float4*)(Bc + bcn);
                rb1[u] = *(const float4*)(Bc + bcn + 4);
                rc0[u] = *(const float4*)(Cc + bcn);
                rc1[u] = *(const float4*)(Cc + bcn + 4);
                rx[u]  = zx[row0 + (size_t)tn * DPROJ + col_x];
                rz[u]  = zx[row0 + (size_t)tn * DPROJ + col_z];
                rda[u] = dtA[dt_base + (size_t)tn * NHEADS];
            }

            // fused depthwise conv4 + silu -> x
            const float cv = bx + w0 * xh0 + w1 * xh1 + w2 * xh2 + w3 * xraw;
            const float xv = cv * sigm(cv);
            const float coef = da.x * xv;
            const float dAv  = da.y;

            const float Bv[8] = {b0.x, b0.y, b0.z, b0.w, b1.x, b1.y, b1.z, b1.w};
            const float Cv[8] = {c0.x, c0.y, c0.z, c0.w, c1.x, c1.y, c1.z, c1.w};
            float acc0 = 0.0f, acc1 = 0.0f;
            #pragma unroll
            for (int j = 0; j < 4; j++) {
                st[j] = dAv * st[j] + coef * Bv[j];
                acc0 += st[j] * Cv[j];
            }
            #pragma unroll
            for (int j = 4; j < 8; j++) {
                st[j] = dAv * st[j] + coef * Bv[j];
                acc1 += st[j] * Cv[j];
            }
            float acc = acc0 + acc1;
            acc += __shfl_xor(acc, 4, 64);
            acc += __shfl_xor(acc, 8, 64);
            acc += __shfl_xor(acc, 16, 64);
            acc += __shfl_xor(acc, 32, 64);

            if (ng == 0) {
                const float y  = acc + Dh * xv;
                const float zg = zraw * sigm(zraw);
                out[o_base + (size_t)t * DINNER] = y * zg;
            }

            // rotate conv history
            xh0 = xh1; xh1 = xh2; xh2 = xraw;
        }
    }
}

// ---------------------------------------------------------------------------
extern "C" void kernel_launch(void* const* d_in, const int* in_sizes, int n_in,
                              void* d_out, int out_size, void* d_ws, size_t ws_size,
                              hipStream_t stream) {
    const float* zxbcdt   = (const float*)d_in[0];
    const float* conv_w   = (const float*)d_in[1];
    const float* conv_b   = (const float*)d_in[2];
    const float* dt_bias  = (const float*)d_in[3];
    const float* a_log    = (const float*)d_in[4];
    const float* d_param  = (const float*)d_in[5];
    const float* dt_scale = (const float*)d_in[6];
    const float* init_st  = (const float*)d_in[7];
    const int* dt_min_p   = (const int*)d_in[11];
    const int* dt_max_p   = (const int*)d_in[12];
    float* out = (float*)d_out;

    // workspace: 5 MiB
    char* ws = (char*)d_ws;
    const size_t n_bl = (size_t)BSZ * LLEN;                          // 4096
    float*  Bc  = (float*)ws;  ws += n_bl * DSTATE * sizeof(float);  // 2 MiB
    float*  Cc  = (float*)ws;  ws += n_bl * DSTATE * sizeof(float);  // 2 MiB
    float2* dtA = (float2*)ws; ws += n_bl * NHEADS * sizeof(float2); // 1 MiB

    pre_kernel<<<dim3((unsigned)n_bl), 256, 0, stream>>>(
        zxbcdt, conv_w, conv_b, dt_bias, a_log, dt_scale,
        dt_min_p, dt_max_p, Bc, Cc, dtA);

    scan_kernel<<<dim3(4, NHEADS, BSZ), 256, 0, stream>>>(
        zxbcdt, conv_w, conv_b, Bc, Cc, dtA, d_param, init_st, out);
}

// Round 5
// 666.599 us; speedup vs baseline: 2.1794x; 1.7035x over previous
//
#include <hip/hip_runtime.h>
#include <hip/hip_bf16.h>

#define BSZ 2
#define LLEN 2048
#define NHEADS 32
#define HEADDIM 64
#define DSTATE 128
#define DCONV 4
#define DINNER (NHEADS * HEADDIM)                  // 2048
#define DPROJ  (2 * DINNER + 2 * DSTATE + NHEADS)  // 4384
#define Q 256                                      // scan chunk length
#define NCHUNK (LLEN / Q)                          // 8

__device__ __forceinline__ float sigm(float x) { return 1.0f / (1.0f + __expf(-x)); }

// Robust python-int scalar read (int32 bits or float32 bits).
__device__ __forceinline__ float int_scalar(const int* p) {
    int i = *p;
    if (i >= 0 && i <= 1000000) return (float)i;
    return __int_as_float(i);
}

// ---------------------------------------------------------------------------
// Kernel 1: B/C conv channels + dt/dA into fp32 workspace.
// ---------------------------------------------------------------------------
__global__ __launch_bounds__(256) void pre_kernel(
    const float* __restrict__ zx, const float* __restrict__ cw,
    const float* __restrict__ cb, const float* __restrict__ dtb,
    const float* __restrict__ alog, const float* __restrict__ dts,
    const int* __restrict__ mn_p, const int* __restrict__ mx_p,
    float* __restrict__ Bc, float* __restrict__ Cc,
    float2* __restrict__ dtA)
{
    const int bl  = blockIdx.x;            // 0 .. B*L-1
    const int b   = bl / LLEN;
    const int l   = bl % LLEN;
    const int tid = threadIdx.x;           // 0..255 == 2*DSTATE channels

    {
        const int c = DINNER + tid;        // conv channel (B/C region)
        float acc = cb[c];
        #pragma unroll
        for (int k = 0; k < DCONV; k++) {
            int lk = l - (DCONV - 1) + k;
            if (lk >= 0) {
                acc += cw[(size_t)c * DCONV + k] *
                       zx[((size_t)b * LLEN + lk) * DPROJ + DINNER + c];
            }
        }
        float v = acc * sigm(acc);
        if (tid < DSTATE) Bc[(size_t)bl * DSTATE + tid] = v;
        else              Cc[(size_t)bl * DSTATE + (tid - DSTATE)] = v;
    }

    if (tid < NHEADS) {
        float raw = zx[(size_t)bl * DPROJ + (DPROJ - NHEADS) + tid];
        float v   = raw * dts[tid] + dtb[tid];
        float sp  = (v > 20.0f) ? v : log1pf(__expf(v));
        float dt  = fminf(fmaxf(sp, int_scalar(mn_p)), int_scalar(mx_p));
        float A   = -__expf(alog[tid]);
        dtA[(size_t)bl * NHEADS + tid] = make_float2(dt, __expf(dt * A));
    }
}

// ---------------------------------------------------------------------------
// Phase A: per-chunk local state (zero initial state) + total decay.
// Grid (4*NCHUNK, 32, 2) x 256. Wave owns 4 p; lane=(ng<<2)|pidx; 8 n/lane.
// ---------------------------------------------------------------------------
__global__ __launch_bounds__(256, 8) void state_kernel(
    const float* __restrict__ zx, const float* __restrict__ cw,
    const float* __restrict__ cb,
    const float* __restrict__ Bc, const float2* __restrict__ dtA,
    float* __restrict__ SA, float* __restrict__ dtot)
{
    const int pb   = blockIdx.x & 3;
    const int c    = blockIdx.x >> 2;    // chunk
    const int h    = blockIdx.y;
    const int b    = blockIdx.z;
    const int tid  = threadIdx.x;
    const int wave = tid >> 6;
    const int lane = tid & 63;
    const int p    = pb * 16 + wave * 4 + (lane & 3);
    const int ng   = lane >> 2;
    const int n0   = ng * 8;
    const int t0   = c * Q;

    const int cx = h * HEADDIM + p;
    const float w0 = cw[(size_t)cx * DCONV + 0];
    const float w1 = cw[(size_t)cx * DCONV + 1];
    const float w2 = cw[(size_t)cx * DCONV + 2];
    const float w3 = cw[(size_t)cx * DCONV + 3];
    const float bx = cb[cx];

    const float*  pB = Bc  + (size_t)b * LLEN * DSTATE + (size_t)t0 * DSTATE + n0;
    const float*  px = zx  + (size_t)b * LLEN * DPROJ  + (size_t)t0 * DPROJ + DINNER + cx;
    const float2* pd = dtA + ((size_t)b * LLEN + t0) * NHEADS + h;

    // conv history entering the chunk
    float xh0 = 0.0f, xh1 = 0.0f, xh2 = 0.0f;
    if (c > 0) {
        xh0 = px[-3 * DPROJ];
        xh1 = px[-2 * DPROJ];
        xh2 = px[-1 * DPROJ];
    }

    float st[8];
    #pragma unroll
    for (int j = 0; j < 8; j++) st[j] = 0.0f;
    float aprod = 1.0f;

    // depth-2 ring
    float4 rb0[2], rb1[2]; float rx[2]; float2 rda[2];
    #pragma unroll
    for (int u = 0; u < 2; u++) {
        rb0[u] = *(const float4*)(pB + (size_t)u * DSTATE);
        rb1[u] = *(const float4*)(pB + (size_t)u * DSTATE + 4);
        rx[u]  = px[(size_t)u * DPROJ];
        rda[u] = pd[(size_t)u * NHEADS];
    }

    for (int tb = 0; tb < Q; tb += 2) {
        #pragma unroll
        for (int u = 0; u < 2; u++) {
            const int t = tb + u;
            const float4 b0 = rb0[u], b1 = rb1[u];
            const float  xraw = rx[u];
            const float2 da   = rda[u];

            int tn = t + 2; if (tn > Q - 1) tn = Q - 1;
            rb0[u] = *(const float4*)(pB + (size_t)tn * DSTATE);
            rb1[u] = *(const float4*)(pB + (size_t)tn * DSTATE + 4);
            rx[u]  = px[(size_t)tn * DPROJ];
            rda[u] = pd[(size_t)tn * NHEADS];

            const float cv = bx + w0 * xh0 + w1 * xh1 + w2 * xh2 + w3 * xraw;
            const float xv = cv * sigm(cv);
            const float coef = da.x * xv;
            const float dAv  = da.y;
            aprod *= dAv;

            const float Bv[8] = {b0.x, b0.y, b0.z, b0.w, b1.x, b1.y, b1.z, b1.w};
            #pragma unroll
            for (int j = 0; j < 8; j++) st[j] = dAv * st[j] + coef * Bv[j];

            xh0 = xh1; xh1 = xh2; xh2 = xraw;
        }
    }

    const size_t sbase = ((size_t)(b * NHEADS + h) * NCHUNK + c) * HEADDIM * DSTATE
                       + (size_t)p * DSTATE + n0;
    *(float4*)(SA + sbase)     = make_float4(st[0], st[1], st[2], st[3]);
    *(float4*)(SA + sbase + 4) = make_float4(st[4], st[5], st[6], st[7]);
    if (tid == 0) dtot[(size_t)(b * NHEADS + h) * NCHUNK + c] = aprod;
}

// ---------------------------------------------------------------------------
// Phase B: sequential chunk combine per (b,h). SA[c] := state ENTERING chunk c.
// ---------------------------------------------------------------------------
__global__ __launch_bounds__(256) void combine_kernel(
    const float* __restrict__ init_state, const float* __restrict__ dtot,
    float* __restrict__ SA)
{
    const int h = blockIdx.x, b = blockIdx.y, tid = threadIdx.x;
    const size_t hd = (size_t)(b * NHEADS + h);
    const size_t eb = (size_t)tid * 32;            // 32 elems per thread

    float4 run[8];
    const float4* pi = (const float4*)(init_state + hd * HEADDIM * DSTATE + eb);
    #pragma unroll
    for (int k = 0; k < 8; k++) run[k] = pi[k];

    for (int c = 0; c < NCHUNK; c++) {
        const float d = dtot[hd * NCHUNK + c];
        float4* ps = (float4*)(SA + (hd * NCHUNK + c) * HEADDIM * DSTATE + eb);
        #pragma unroll
        for (int k = 0; k < 8; k++) {
            float4 loc = ps[k];
            float4 sin = run[k];
            ps[k] = sin;                            // state entering chunk c
            run[k].x = d * sin.x + loc.x;
            run[k].y = d * sin.y + loc.y;
            run[k].z = d * sin.z + loc.z;
            run[k].w = d * sin.w + loc.w;
        }
    }
}

// ---------------------------------------------------------------------------
// Phase C: per-chunk full scan from true incoming state, with outputs.
// ---------------------------------------------------------------------------
__global__ __launch_bounds__(256, 4) void out_kernel(
    const float* __restrict__ zx, const float* __restrict__ cw,
    const float* __restrict__ cb,
    const float* __restrict__ Bc, const float* __restrict__ Cc,
    const float2* __restrict__ dtA,
    const float* __restrict__ d_param, const float* __restrict__ SA,
    float* __restrict__ out)
{
    const int pb   = blockIdx.x & 3;
    const int c    = blockIdx.x >> 2;
    const int h    = blockIdx.y;
    const int b    = blockIdx.z;
    const int tid  = threadIdx.x;
    const int wave = tid >> 6;
    const int lane = tid & 63;
    const int p    = pb * 16 + wave * 4 + (lane & 3);
    const int ng   = lane >> 2;
    const int n0   = ng * 8;
    const int t0   = c * Q;

    const int cx = h * HEADDIM + p;
    const float w0 = cw[(size_t)cx * DCONV + 0];
    const float w1 = cw[(size_t)cx * DCONV + 1];
    const float w2 = cw[(size_t)cx * DCONV + 2];
    const float w3 = cw[(size_t)cx * DCONV + 3];
    const float bx = cb[cx];
    const float Dh = d_param[h];

    const float*  pB = Bc  + (size_t)b * LLEN * DSTATE + (size_t)t0 * DSTATE + n0;
    const float*  pC = Cc  + (size_t)b * LLEN * DSTATE + (size_t)t0 * DSTATE + n0;
    const float*  px = zx  + (size_t)b * LLEN * DPROJ  + (size_t)t0 * DPROJ + DINNER + cx;
    const float*  pz = zx  + (size_t)b * LLEN * DPROJ  + (size_t)t0 * DPROJ + cx;
    const float2* pd = dtA + ((size_t)b * LLEN + t0) * NHEADS + h;
    float*        po = out + (size_t)b * LLEN * DINNER + (size_t)t0 * DINNER + cx;

    float xh0 = 0.0f, xh1 = 0.0f, xh2 = 0.0f;
    if (c > 0) {
        xh0 = px[-3 * DPROJ];
        xh1 = px[-2 * DPROJ];
        xh2 = px[-1 * DPROJ];
    }

    float st[8];
    {
        const size_t sbase = ((size_t)(b * NHEADS + h) * NCHUNK + c) * HEADDIM * DSTATE
                           + (size_t)p * DSTATE + n0;
        float4 s0 = *(const float4*)(SA + sbase);
        float4 s1 = *(const float4*)(SA + sbase + 4);
        st[0]=s0.x; st[1]=s0.y; st[2]=s0.z; st[3]=s0.w;
        st[4]=s1.x; st[5]=s1.y; st[6]=s1.z; st[7]=s1.w;
    }

    // depth-2 ring
    float4 rb0[2], rb1[2], rc0[2], rc1[2]; float rx[2], rz[2]; float2 rda[2];
    #pragma unroll
    for (int u = 0; u < 2; u++) {
        rb0[u] = *(const float4*)(pB + (size_t)u * DSTATE);
        rb1[u] = *(const float4*)(pB + (size_t)u * DSTATE + 4);
        rc0[u] = *(const float4*)(pC + (size_t)u * DSTATE);
        rc1[u] = *(const float4*)(pC + (size_t)u * DSTATE + 4);
        rx[u]  = px[(size_t)u * DPROJ];
        rz[u]  = pz[(size_t)u * DPROJ];
        rda[u] = pd[(size_t)u * NHEADS];
    }

    for (int tb = 0; tb < Q; tb += 2) {
        #pragma unroll
        for (int u = 0; u < 2; u++) {
            const int t = tb + u;
            const float4 b0 = rb0[u], b1 = rb1[u];
            const float4 c0 = rc0[u], c1 = rc1[u];
            const float  xraw = rx[u], zraw = rz[u];
            const float2 da   = rda[u];

            int tn = t + 2; if (tn > Q - 1) tn = Q - 1;
            rb0[u] = *(const float4*)(pB + (size_t)tn * DSTATE);
            rb1[u] = *(const float4*)(pB + (size_t)tn * DSTATE + 4);
            rc0[u] = *(const float4*)(pC + (size_t)tn * DSTATE);
            rc1[u] = *(const float4*)(pC + (size_t)tn * DSTATE + 4);
            rx[u]  = px[(size_t)tn * DPROJ];
            rz[u]  = pz[(size_t)tn * DPROJ];
            rda[u] = pd[(size_t)tn * NHEADS];

            const float cv = bx + w0 * xh0 + w1 * xh1 + w2 * xh2 + w3 * xraw;
            const float xv = cv * sigm(cv);
            const float coef = da.x * xv;
            const float dAv  = da.y;

            const float Bv[8] = {b0.x, b0.y, b0.z, b0.w, b1.x, b1.y, b1.z, b1.w};
            const float Cv[8] = {c0.x, c0.y, c0.z, c0.w, c1.x, c1.y, c1.z, c1.w};
            float acc0 = 0.0f, acc1 = 0.0f;
            #pragma unroll
            for (int j = 0; j < 4; j++) {
                st[j] = dAv * st[j] + coef * Bv[j];
                acc0 += st[j] * Cv[j];
            }
            #pragma unroll
            for (int j = 4; j < 8; j++) {
                st[j] = dAv * st[j] + coef * Bv[j];
                acc1 += st[j] * Cv[j];
            }
            float acc = acc0 + acc1;
            acc += __shfl_xor(acc, 4, 64);
            acc += __shfl_xor(acc, 8, 64);
            acc += __shfl_xor(acc, 16, 64);
            acc += __shfl_xor(acc, 32, 64);

            if (ng == 0) {
                const float y  = acc + Dh * xv;
                const float zg = zraw * sigm(zraw);
                po[(size_t)t * DINNER] = y * zg;
            }

            xh0 = xh1; xh1 = xh2; xh2 = xraw;
        }
    }
}

// ---------------------------------------------------------------------------
extern "C" void kernel_launch(void* const* d_in, const int* in_sizes, int n_in,
                              void* d_out, int out_size, void* d_ws, size_t ws_size,
                              hipStream_t stream) {
    const float* zxbcdt   = (const float*)d_in[0];
    const float* conv_w   = (const float*)d_in[1];
    const float* conv_b   = (const float*)d_in[2];
    const float* dt_bias  = (const float*)d_in[3];
    const float* a_log    = (const float*)d_in[4];
    const float* d_param  = (const float*)d_in[5];
    const float* dt_scale = (const float*)d_in[6];
    const float* init_st  = (const float*)d_in[7];
    const int* dt_min_p   = (const int*)d_in[11];
    const int* dt_max_p   = (const int*)d_in[12];
    float* out = (float*)d_out;

    // workspace: 2 + 2 + 1 + 16.8 MB + 2 KB  ~= 21.8 MiB
    char* ws = (char*)d_ws;
    const size_t n_bl = (size_t)BSZ * LLEN;                          // 4096
    float*  Bc  = (float*)ws;  ws += n_bl * DSTATE * sizeof(float);  // 2 MiB
    float*  Cc  = (float*)ws;  ws += n_bl * DSTATE * sizeof(float);  // 2 MiB
    float2* dtA = (float2*)ws; ws += n_bl * NHEADS * sizeof(float2); // 1 MiB
    float*  SA  = (float*)ws;                                        // 16.8 MiB
    ws += (size_t)BSZ * NHEADS * NCHUNK * HEADDIM * DSTATE * sizeof(float);
    float*  dtot = (float*)ws; ws += (size_t)BSZ * NHEADS * NCHUNK * sizeof(float);

    pre_kernel<<<dim3((unsigned)n_bl), 256, 0, stream>>>(
        zxbcdt, conv_w, conv_b, dt_bias, a_log, dt_scale,
        dt_min_p, dt_max_p, Bc, Cc, dtA);

    state_kernel<<<dim3(4 * NCHUNK, NHEADS, BSZ), 256, 0, stream>>>(
        zxbcdt, conv_w, conv_b, Bc, dtA, SA, dtot);

    combine_kernel<<<dim3(NHEADS, BSZ), 256, 0, stream>>>(
        init_st, dtot, SA);

    out_kernel<<<dim3(4 * NCHUNK, NHEADS, BSZ), 256, 0, stream>>>(
        zxbcdt, conv_w, conv_b, Bc, Cc, dtA, d_param, SA, out);
}